// Round 1
// baseline (160.055 us; speedup 1.0000x reference)
//
#include <hip/hip_runtime.h>
#include <hip/hip_bf16.h>

#define DI __device__ __forceinline__

using bf16x8 = __attribute__((ext_vector_type(8))) short;
using f32x4  = __attribute__((ext_vector_type(4))) float;
using u16    = unsigned short;
using u16x4  = __attribute__((ext_vector_type(4))) unsigned short;

constexpr int Bc = 2, Sc = 2048, Hc = 768, NHc = 12, HDc = 64;
constexpr int Mc = Bc * Sc;                 // 4096 rows
constexpr float L2E = 1.4426950408889634f;

DI u16 f2bf(float f) {
  union { float f; unsigned u; } c; c.f = f;
  unsigned u = c.u;
  return (u16)((u + 0x7fffu + ((u >> 16) & 1u)) >> 16);   // RNE
}

DI void gload_lds16(const void* g, void* l) {
  __builtin_amdgcn_global_load_lds(
      (__attribute__((address_space(1))) void*)(g),
      (__attribute__((address_space(3))) void*)(l), 16, 0, 0);
}

// ---------------- prep kernels ----------------

__global__ void cvt_bf16(const float* __restrict__ x, u16* __restrict__ y, int n4) {
  int i = blockIdx.x * 256 + threadIdx.x;
  if (i >= n4) return;
  float4 v = reinterpret_cast<const float4*>(x)[i];
  u16x4 o;
  o[0] = f2bf(v.x); o[1] = f2bf(v.y); o[2] = f2bf(v.z); o[3] = f2bf(v.w);
  reinterpret_cast<u16x4*>(y)[i] = o;
}

// Wt[n][k] = W[k][n], bf16
__global__ void wtrans(const float* __restrict__ Wq, const float* __restrict__ Wk,
                       const float* __restrict__ Wv, const float* __restrict__ Wo,
                       u16* __restrict__ Tq, u16* __restrict__ Tk,
                       u16* __restrict__ Tv, u16* __restrict__ To) {
  __shared__ float tile[32][33];
  const float* W; u16* T;
  switch (blockIdx.z) {
    case 0:  W = Wq; T = Tq; break;
    case 1:  W = Wk; T = Tk; break;
    case 2:  W = Wv; T = Tv; break;
    default: W = Wo; T = To; break;
  }
  int tx = threadIdx.x, ty = threadIdx.y;
  int n0 = blockIdx.x * 32, k0 = blockIdx.y * 32;
#pragma unroll
  for (int j = 0; j < 4; ++j) tile[ty + j * 8][tx] = W[(k0 + ty + j * 8) * Hc + n0 + tx];
  __syncthreads();
#pragma unroll
  for (int j = 0; j < 4; ++j) T[(n0 + ty + j * 8) * Hc + k0 + tx] = f2bf(tile[tx][ty + j * 8]);
}

// ---------------- GEMM core (C[m][n] = sum_k A[m][k]*Bt[n][k]) ----------------
// 128x128 tile, BK=32, 4 waves in 2x2, each wave 64x64 via 4x4 16x16x32 mfma.
// LDS chunks (16B) XOR-swizzled by ((row>>1)&3) to kill ds_read bank conflicts.

DI void gemm_core(const u16* __restrict__ Ag, const u16* __restrict__ Btg,
                  u16* Asm, u16* Bsm, int m0, int n0,
                  int tid, int lane, int wr, int wc, f32x4 acc[4][4]) {
  const int lo = lane & 15, hi = lane >> 4;
  const int r1 = tid >> 2, c1 = tid & 3;
  for (int kt = 0; kt < Hc / 32; ++kt) {
    const int k0 = kt * 32;
    {
      int row = r1, cg = c1 ^ ((row >> 1) & 3);
      gload_lds16(Ag  + (size_t)(row + m0) * Hc + k0 + cg * 8, Asm + tid * 8);
      gload_lds16(Btg + (size_t)(row + n0) * Hc + k0 + cg * 8, Bsm + tid * 8);
      row = r1 + 64; cg = c1 ^ ((row >> 1) & 3);
      gload_lds16(Ag  + (size_t)(row + m0) * Hc + k0 + cg * 8, Asm + (tid + 256) * 8);
      gload_lds16(Btg + (size_t)(row + n0) * Hc + k0 + cg * 8, Bsm + (tid + 256) * 8);
    }
    __syncthreads();
    bf16x8 af[4], bf[4];
#pragma unroll
    for (int m = 0; m < 4; ++m) {
      int rowa = wr * 64 + m * 16 + lo;
      af[m] = *reinterpret_cast<const bf16x8*>(Asm + rowa * 32 + ((hi ^ ((rowa >> 1) & 3)) * 8));
      int rowb = wc * 64 + m * 16 + lo;
      bf[m] = *reinterpret_cast<const bf16x8*>(Bsm + rowb * 32 + ((hi ^ ((rowb >> 1) & 3)) * 8));
    }
#pragma unroll
    for (int m = 0; m < 4; ++m)
#pragma unroll
      for (int n = 0; n < 4; ++n)
        acc[m][n] = __builtin_amdgcn_mfma_f32_16x16x32_bf16(af[m], bf[n], acc[m][n], 0, 0, 0);
    __syncthreads();
  }
}

// ---------------- QKV projection ----------------
// z=0: Q (scaled by 1/8) -> [b,h,s,d]; z=1: K -> [b,h,s,d]; z=2: V -> [b,h,d,s] (transposed)

__launch_bounds__(256)
__global__ void qkv_gemm(const u16* __restrict__ Xb,
                         const u16* __restrict__ Wtq, const u16* __restrict__ Wtk,
                         const u16* __restrict__ Wtv,
                         const float* __restrict__ bq, const float* __restrict__ bk,
                         const float* __restrict__ bv,
                         u16* __restrict__ Qo, u16* __restrict__ Ko, u16* __restrict__ Vto) {
  __shared__ __attribute__((aligned(16))) u16 Asm[128 * 32];
  __shared__ __attribute__((aligned(16))) u16 Bsm[128 * 32];
  const int tid = threadIdx.x, lane = tid & 63, w = tid >> 6;
  const int wr = w >> 1, wc = w & 1;
  const int m0 = blockIdx.x * 128, n0 = blockIdx.y * 128;
  const int z = blockIdx.z;
  const u16* Bt = (z == 0) ? Wtq : ((z == 1) ? Wtk : Wtv);
  const float* bias = (z == 0) ? bq : ((z == 1) ? bk : bv);
  f32x4 acc[4][4] = {};
  gemm_core(Xb, Bt, Asm, Bsm, m0, n0, tid, lane, wr, wc, acc);
  const int lo = lane & 15, hi = lane >> 4;
  const float scl = (z == 0) ? 0.125f : 1.0f;
#pragma unroll
  for (int m = 0; m < 4; ++m)
#pragma unroll
    for (int n = 0; n < 4; ++n)
#pragma unroll
      for (int r = 0; r < 4; ++r) {
        int gm = m0 + wr * 64 + m * 16 + hi * 4 + r;
        int gn = n0 + wc * 64 + n * 16 + lo;
        float v = (acc[m][n][r] + bias[gn]) * scl;
        int b = gm >> 11, s = gm & 2047, h = gn >> 6, d = gn & 63;
        u16 bv16 = f2bf(v);
        if (z == 2) Vto[((b * NHc + h) * HDc + d) * Sc + s] = bv16;
        else {
          int idx = (((b * NHc + h) * Sc) + s) * HDc + d;
          if (z == 0) Qo[idx] = bv16; else Ko[idx] = bv16;
        }
      }
}

// ---------------- output projection ----------------

__launch_bounds__(256)
__global__ void out_gemm(const u16* __restrict__ Ctx, const u16* __restrict__ Wto,
                         const float* __restrict__ bo, float* __restrict__ out) {
  __shared__ __attribute__((aligned(16))) u16 Asm[128 * 32];
  __shared__ __attribute__((aligned(16))) u16 Bsm[128 * 32];
  const int tid = threadIdx.x, lane = tid & 63, w = tid >> 6;
  const int wr = w >> 1, wc = w & 1;
  const int m0 = blockIdx.x * 128, n0 = blockIdx.y * 128;
  f32x4 acc[4][4] = {};
  gemm_core(Ctx, Wto, Asm, Bsm, m0, n0, tid, lane, wr, wc, acc);
  const int lo = lane & 15, hi = lane >> 4;
#pragma unroll
  for (int m = 0; m < 4; ++m)
#pragma unroll
    for (int n = 0; n < 4; ++n)
#pragma unroll
      for (int r = 0; r < 4; ++r) {
        int gm = m0 + wr * 64 + m * 16 + hi * 4 + r;
        int gn = n0 + wc * 64 + n * 16 + lo;
        out[(size_t)gm * Hc + gn] = acc[m][n][r] + bo[gn];
      }
}

// ---------------- flash attention ----------------
// grid (S/64, B*NH). 4 waves, each owns 16 q-rows. KVBLK=64.
// Q pre-scaled by 1/8. K tile [kv][d], Vt tile [d][kv] in LDS, 16B chunks
// XOR-swizzled by (row&7). P staged per-wave in swizzled LDS for the PV mfma.

__launch_bounds__(256)
__global__ void attn(const u16* __restrict__ Qg, const u16* __restrict__ Kg,
                     const u16* __restrict__ Vtg, const int* __restrict__ maskg,
                     u16* __restrict__ ctxg) {
  __shared__ __attribute__((aligned(16))) u16 Ksm[64 * 64];
  __shared__ __attribute__((aligned(16))) u16 Vsm[64 * 64];
  __shared__ __attribute__((aligned(16))) u16 Psm[4][16 * 64];
  const int tid = threadIdx.x, lane = tid & 63, w = tid >> 6;
  const int lo = lane & 15, hi = lane >> 4;
  const int q0 = blockIdx.x * 64;
  const int bh = blockIdx.y;                 // 0..23
  const int b = bh / NHc, h = bh % NHc;
  const u16* Qh = Qg + (size_t)bh * Sc * HDc;
  const u16* Kh = Kg + (size_t)bh * Sc * HDc;
  const u16* Vh = Vtg + (size_t)bh * HDc * Sc;
  const int* maskb = maskg + b * Sc;

  // Q fragments live in registers for the whole kv loop
  const int qrow = q0 + w * 16 + lo;
  bf16x8 qf[2];
  qf[0] = *reinterpret_cast<const bf16x8*>(Qh + (size_t)qrow * HDc + hi * 8);
  qf[1] = *reinterpret_cast<const bf16x8*>(Qh + (size_t)qrow * HDc + 32 + hi * 8);

  f32x4 oacc[4] = {};
  float mrow[4] = {-1e30f, -1e30f, -1e30f, -1e30f};
  float lrow[4] = {0.f, 0.f, 0.f, 0.f};

  const int ch1 = tid, row1 = ch1 >> 3, cs1 = ch1 & 7, cg1 = cs1 ^ (row1 & 7);
  const int ch2 = tid + 256, row2 = ch2 >> 3, cs2 = ch2 & 7, cg2 = cs2 ^ (row2 & 7);

  for (int kv0 = 0; kv0 < Sc; kv0 += 64) {
    // stage K[kv0..+64][0..64] and Vt[0..64][kv0..+64] (source-swizzled)
    gload_lds16(Kh + (size_t)(kv0 + row1) * HDc + cg1 * 8, Ksm + ch1 * 8);
    gload_lds16(Kh + (size_t)(kv0 + row2) * HDc + cg2 * 8, Ksm + ch2 * 8);
    gload_lds16(Vh + (size_t)row1 * Sc + kv0 + cg1 * 8, Vsm + ch1 * 8);
    gload_lds16(Vh + (size_t)row2 * Sc + kv0 + cg2 * 8, Vsm + ch2 * 8);
    __syncthreads();

    // S = Q K^T (Q pre-scaled)
    f32x4 sacc[4] = {};
#pragma unroll
    for (int n = 0; n < 4; ++n) {
#pragma unroll
      for (int ks = 0; ks < 2; ++ks) {
        int row = n * 16 + lo;
        bf16x8 kf = *reinterpret_cast<const bf16x8*>(
            Ksm + row * 64 + (((ks * 4 + hi) ^ (row & 7)) * 8));
        sacc[n] = __builtin_amdgcn_mfma_f32_16x16x32_bf16(qf[ks], kf, sacc[n], 0, 0, 0);
      }
      int kp = kv0 + n * 16 + lo;
      float add = (1.0f - (float)maskb[kp]) * -10000.0f;
#pragma unroll
      for (int r = 0; r < 4; ++r) sacc[n][r] += add;
    }

    // online softmax (rows live in 16-lane groups)
    float tmax[4];
#pragma unroll
    for (int r = 0; r < 4; ++r)
      tmax[r] = fmaxf(fmaxf(sacc[0][r], sacc[1][r]), fmaxf(sacc[2][r], sacc[3][r]));
#pragma unroll
    for (int off = 1; off < 16; off <<= 1)
#pragma unroll
      for (int r = 0; r < 4; ++r) tmax[r] = fmaxf(tmax[r], __shfl_xor(tmax[r], off, 64));

    float scale[4], psum[4];
#pragma unroll
    for (int r = 0; r < 4; ++r) {
      float mnew = fmaxf(mrow[r], tmax[r]);
      scale[r] = exp2f((mrow[r] - mnew) * L2E);
      mrow[r] = mnew;
      psum[r] = 0.f;
    }
#pragma unroll
    for (int n = 0; n < 4; ++n)
#pragma unroll
      for (int r = 0; r < 4; ++r) {
        float p = exp2f((sacc[n][r] - mrow[r]) * L2E);
        sacc[n][r] = p;
        psum[r] += p;
      }
#pragma unroll
    for (int off = 1; off < 16; off <<= 1)
#pragma unroll
      for (int r = 0; r < 4; ++r) psum[r] += __shfl_xor(psum[r], off, 64);
#pragma unroll
    for (int r = 0; r < 4; ++r) lrow[r] = lrow[r] * scale[r] + psum[r];
#pragma unroll
    for (int n = 0; n < 4; ++n)
#pragma unroll
      for (int r = 0; r < 4; ++r) oacc[n][r] *= scale[r];

    // P -> per-wave swizzled LDS, then PV mfma
    u16* Pw = &Psm[w][0];
#pragma unroll
    for (int n = 0; n < 4; ++n)
#pragma unroll
      for (int r = 0; r < 4; ++r) {
        int prow = hi * 4 + r, pcol = n * 16 + lo;
        Pw[prow * 64 + (pcol ^ ((prow & 7) << 3))] = f2bf(sacc[n][r]);
      }
#pragma unroll
    for (int n = 0; n < 4; ++n) {
#pragma unroll
      for (int ks = 0; ks < 2; ++ks) {
        bf16x8 pf = *reinterpret_cast<const bf16x8*>(
            Pw + lo * 64 + ((ks * 32 + hi * 8) ^ ((lo & 7) << 3)));
        int vrow = n * 16 + lo;
        bf16x8 vf = *reinterpret_cast<const bf16x8*>(
            Vsm + vrow * 64 + (((ks * 4 + hi) ^ (vrow & 7)) * 8));
        oacc[n] = __builtin_amdgcn_mfma_f32_16x16x32_bf16(pf, vf, oacc[n], 0, 0, 0);
      }
    }
    __syncthreads();
  }

  // finalize: divide by l, write ctx[b,s, h*64+d] bf16
#pragma unroll
  for (int r = 0; r < 4; ++r) {
    float inv = 1.0f / lrow[r];
#pragma unroll
    for (int n = 0; n < 4; ++n) {
      int gq = q0 + w * 16 + hi * 4 + r;
      int gd = n * 16 + lo;
      ctxg[(size_t)(b * Sc + gq) * Hc + h * HDc + gd] = f2bf(oacc[n][r] * inv);
    }
  }
}

// ---------------- launch ----------------

extern "C" void kernel_launch(void* const* d_in, const int* in_sizes, int n_in,
                              void* d_out, int out_size, void* d_ws, size_t ws_size,
                              hipStream_t stream) {
  const float* hs  = (const float*)d_in[0];
  const int* mask  = (const int*)d_in[1];
  const float* Wq  = (const float*)d_in[2];
  const float* bq  = (const float*)d_in[3];
  const float* Wk  = (const float*)d_in[4];
  const float* bk  = (const float*)d_in[5];
  const float* Wv  = (const float*)d_in[6];
  const float* bv  = (const float*)d_in[7];
  const float* Wo  = (const float*)d_in[8];
  const float* bo  = (const float*)d_in[9];

  char* ws = (char*)d_ws;
  u16* Xb  = (u16*)(ws);                      // 4096x768 bf16        (6.29 MB)
  u16* Wtq = (u16*)(ws + 6291456);            // 4x 768x768 bf16      (4.72 MB)
  u16* Wtk = Wtq + 589824;
  u16* Wtv = Wtk + 589824;
  u16* Wto = Wtv + 589824;
  u16* Qb  = (u16*)(ws + 11010048);           // [24][2048][64] bf16
  u16* Kb  = Qb + 3145728;                    // [24][2048][64]
  u16* Vtb = Kb + 3145728;                    // [24][64][2048]
  u16* Ctx = Vtb + 3145728;                   // 4096x768 bf16
  // total ws use: 36,175,872 bytes

  cvt_bf16<<<(Mc * Hc / 4 + 255) / 256, 256, 0, stream>>>(hs, Xb, Mc * Hc / 4);
  wtrans<<<dim3(24, 24, 4), dim3(32, 8), 0, stream>>>(Wq, Wk, Wv, Wo, Wtq, Wtk, Wtv, Wto);
  qkv_gemm<<<dim3(32, 6, 3), 256, 0, stream>>>(Xb, Wtq, Wtk, Wtv, bq, bk, bv, Qb, Kb, Vtb);
  attn<<<dim3(Sc / 64, Bc * NHc), 256, 0, stream>>>(Qb, Kb, Vtb, mask, Ctx);
  out_gemm<<<dim3(32, 6), 256, 0, stream>>>(Ctx, Wto, bo, (float*)d_out);
}

// Round 2
// 141.028 us; speedup vs baseline: 1.1349x; 1.1349x over previous
//
#include <hip/hip_runtime.h>
#include <hip/hip_bf16.h>

#define DI __device__ __forceinline__

using bf16x8 = __attribute__((ext_vector_type(8))) short;
using f32x4  = __attribute__((ext_vector_type(4))) float;
using u16    = unsigned short;
using u16x4  = __attribute__((ext_vector_type(4))) unsigned short;

constexpr int Bc = 2, Sc = 2048, Hc = 768, NHc = 12, HDc = 64;
constexpr int Mc = Bc * Sc;                 // 4096 rows
constexpr float L2E = 1.4426950408889634f;

DI u16 f2bf(float f) {
  union { float f; unsigned u; } c; c.f = f;
  unsigned u = c.u;
  return (u16)((u + 0x7fffu + ((u >> 16) & 1u)) >> 16);   // RNE
}

DI unsigned f2bf2(float a, float b) {
  float2 t; t.x = a; t.y = b;
  __hip_bfloat162 h = __float22bfloat162_rn(t);   // v_cvt_pk_bf16_f32
  union { __hip_bfloat162 h; unsigned u; } c; c.h = h;
  return c.u;
}

DI void gload_lds16(const void* g, void* l) {
  __builtin_amdgcn_global_load_lds(
      (__attribute__((address_space(1))) void*)(g),
      (__attribute__((address_space(3))) void*)(l), 16, 0, 0);
}

// ---------------- prep kernels ----------------

__global__ void cvt_bf16(const float* __restrict__ x, u16* __restrict__ y, int n4) {
  int i = blockIdx.x * 256 + threadIdx.x;
  if (i >= n4) return;
  float4 v = reinterpret_cast<const float4*>(x)[i];
  u16x4 o;
  o[0] = f2bf(v.x); o[1] = f2bf(v.y); o[2] = f2bf(v.z); o[3] = f2bf(v.w);
  reinterpret_cast<u16x4*>(y)[i] = o;
}

// Wt[n][k] = W[k][n], bf16
__global__ void wtrans(const float* __restrict__ Wq, const float* __restrict__ Wk,
                       const float* __restrict__ Wv, const float* __restrict__ Wo,
                       u16* __restrict__ Tq, u16* __restrict__ Tk,
                       u16* __restrict__ Tv, u16* __restrict__ To) {
  __shared__ float tile[32][33];
  const float* W; u16* T;
  switch (blockIdx.z) {
    case 0:  W = Wq; T = Tq; break;
    case 1:  W = Wk; T = Tk; break;
    case 2:  W = Wv; T = Tv; break;
    default: W = Wo; T = To; break;
  }
  int tx = threadIdx.x, ty = threadIdx.y;
  int n0 = blockIdx.x * 32, k0 = blockIdx.y * 32;
#pragma unroll
  for (int j = 0; j < 4; ++j) tile[ty + j * 8][tx] = W[(k0 + ty + j * 8) * Hc + n0 + tx];
  __syncthreads();
#pragma unroll
  for (int j = 0; j < 4; ++j) T[(n0 + ty + j * 8) * Hc + k0 + tx] = f2bf(tile[tx][ty + j * 8]);
}

// ---------------- GEMM core (C[m][n] = sum_k A[m][k]*Bt[n][k]) ----------------

DI void gemm_core(const u16* __restrict__ Ag, const u16* __restrict__ Btg,
                  u16* Asm, u16* Bsm, int m0, int n0,
                  int tid, int lane, int wr, int wc, f32x4 acc[4][4]) {
  const int lo = lane & 15, hi = lane >> 4;
  const int r1 = tid >> 2, c1 = tid & 3;
  for (int kt = 0; kt < Hc / 32; ++kt) {
    const int k0 = kt * 32;
    {
      int row = r1, cg = c1 ^ ((row >> 1) & 3);
      gload_lds16(Ag  + (size_t)(row + m0) * Hc + k0 + cg * 8, Asm + tid * 8);
      gload_lds16(Btg + (size_t)(row + n0) * Hc + k0 + cg * 8, Bsm + tid * 8);
      row = r1 + 64; cg = c1 ^ ((row >> 1) & 3);
      gload_lds16(Ag  + (size_t)(row + m0) * Hc + k0 + cg * 8, Asm + (tid + 256) * 8);
      gload_lds16(Btg + (size_t)(row + n0) * Hc + k0 + cg * 8, Bsm + (tid + 256) * 8);
    }
    __syncthreads();
    bf16x8 af[4], bf[4];
#pragma unroll
    for (int m = 0; m < 4; ++m) {
      int rowa = wr * 64 + m * 16 + lo;
      af[m] = *reinterpret_cast<const bf16x8*>(Asm + rowa * 32 + ((hi ^ ((rowa >> 1) & 3)) * 8));
      int rowb = wc * 64 + m * 16 + lo;
      bf[m] = *reinterpret_cast<const bf16x8*>(Bsm + rowb * 32 + ((hi ^ ((rowb >> 1) & 3)) * 8));
    }
#pragma unroll
    for (int m = 0; m < 4; ++m)
#pragma unroll
      for (int n = 0; n < 4; ++n)
        acc[m][n] = __builtin_amdgcn_mfma_f32_16x16x32_bf16(af[m], bf[n], acc[m][n], 0, 0, 0);
    __syncthreads();
  }
}

// ---------------- QKV projection ----------------
// z=0: Q (scaled by L2E/8) -> [b,h,s,d]; z=1: K -> [b,h,s,d]; z=2: V -> [b,h,d,s]

__launch_bounds__(256)
__global__ void qkv_gemm(const u16* __restrict__ Xb,
                         const u16* __restrict__ Wtq, const u16* __restrict__ Wtk,
                         const u16* __restrict__ Wtv,
                         const float* __restrict__ bq, const float* __restrict__ bk,
                         const float* __restrict__ bv,
                         u16* __restrict__ Qo, u16* __restrict__ Ko, u16* __restrict__ Vto) {
  __shared__ __attribute__((aligned(16))) u16 Asm[128 * 32];
  __shared__ __attribute__((aligned(16))) u16 Bsm[128 * 32];
  const int tid = threadIdx.x, lane = tid & 63, w = tid >> 6;
  const int wr = w >> 1, wc = w & 1;
  const int m0 = blockIdx.x * 128, n0 = blockIdx.y * 128;
  const int z = blockIdx.z;
  const u16* Bt = (z == 0) ? Wtq : ((z == 1) ? Wtk : Wtv);
  const float* bias = (z == 0) ? bq : ((z == 1) ? bk : bv);
  f32x4 acc[4][4] = {};
  gemm_core(Xb, Bt, Asm, Bsm, m0, n0, tid, lane, wr, wc, acc);
  const int lo = lane & 15, hi = lane >> 4;
  const float scl = (z == 0) ? 0.125f * L2E : 1.0f;    // fold log2(e) into Q
#pragma unroll
  for (int m = 0; m < 4; ++m)
#pragma unroll
    for (int n = 0; n < 4; ++n)
#pragma unroll
      for (int r = 0; r < 4; ++r) {
        int gm = m0 + wr * 64 + m * 16 + hi * 4 + r;
        int gn = n0 + wc * 64 + n * 16 + lo;
        float v = (acc[m][n][r] + bias[gn]) * scl;
        int b = gm >> 11, s = gm & 2047, h = gn >> 6, d = gn & 63;
        u16 bv16 = f2bf(v);
        if (z == 2) Vto[((b * NHc + h) * HDc + d) * Sc + s] = bv16;
        else {
          int idx = (((b * NHc + h) * Sc) + s) * HDc + d;
          if (z == 0) Qo[idx] = bv16; else Ko[idx] = bv16;
        }
      }
}

// ---------------- output projection ----------------

__launch_bounds__(256)
__global__ void out_gemm(const u16* __restrict__ Ctx, const u16* __restrict__ Wto,
                         const float* __restrict__ bo, float* __restrict__ out) {
  __shared__ __attribute__((aligned(16))) u16 Asm[128 * 32];
  __shared__ __attribute__((aligned(16))) u16 Bsm[128 * 32];
  const int tid = threadIdx.x, lane = tid & 63, w = tid >> 6;
  const int wr = w >> 1, wc = w & 1;
  const int m0 = blockIdx.x * 128, n0 = blockIdx.y * 128;
  f32x4 acc[4][4] = {};
  gemm_core(Ctx, Wto, Asm, Bsm, m0, n0, tid, lane, wr, wc, acc);
  const int lo = lane & 15, hi = lane >> 4;
#pragma unroll
  for (int m = 0; m < 4; ++m)
#pragma unroll
    for (int n = 0; n < 4; ++n)
#pragma unroll
      for (int r = 0; r < 4; ++r) {
        int gm = m0 + wr * 64 + m * 16 + hi * 4 + r;
        int gn = n0 + wc * 64 + n * 16 + lo;
        out[(size_t)gm * Hc + gn] = acc[m][n][r] + bo[gn];
      }
}

// ---------------- flash attention ----------------
// 1D grid 768 blocks, XCD-grouped: 3 heads per XCD so K/V stay L2-resident.
// 4 waves x 16 q-rows. KVBLK=64, double-buffered K/V via global_load_lds with
// counted vmcnt(4) + raw s_barrier (no vmcnt(0) drain in the loop).
// Q pre-scaled by L2E/8; softmax in log2 domain; row-sum via ones-MFMA.

__launch_bounds__(256)
__global__ void attn(const u16* __restrict__ Qg, const u16* __restrict__ Kg,
                     const u16* __restrict__ Vtg, const int* __restrict__ maskg,
                     u16* __restrict__ ctxg) {
  __shared__ __attribute__((aligned(16))) u16 Ksm[2][64 * 64];
  __shared__ __attribute__((aligned(16))) u16 Vsm[2][64 * 64];
  __shared__ __attribute__((aligned(16))) u16 Psm[4][16 * 64];
  __shared__ __attribute__((aligned(16))) float Adm[Sc];

  const int tid = threadIdx.x, lane = tid & 63, w = tid >> 6;
  const int lo = lane & 15, hi = lane >> 4;

  // XCD-aware mapping: block id -> (head, q-tile); 96 consecutive-per-XCD
  const int id = blockIdx.x;                  // 0..767
  const int xcd = id & 7, sub = id >> 3;      // sub 0..95
  const int head = xcd * 3 + (sub >> 5);      // 0..23  (= b*NH + h)
  const int q0 = (sub & 31) * 64;
  const int b = head / NHc, h = head % NHc;

  const u16* Qh = Qg + (size_t)head * Sc * HDc;
  const u16* Kh = Kg + (size_t)head * Sc * HDc;
  const u16* Vh = Vtg + (size_t)head * HDc * Sc;
  const int* maskb = maskg + b * Sc;

  // mask adder -> LDS (log2 domain), removes all loop vmem except staging
  for (int i = tid; i < Sc / 4; i += 256) {
    int4 mv = reinterpret_cast<const int4*>(maskb)[i];
    float4 a;
    a.x = (1.0f - (float)mv.x) * (-10000.0f * L2E);
    a.y = (1.0f - (float)mv.y) * (-10000.0f * L2E);
    a.z = (1.0f - (float)mv.z) * (-10000.0f * L2E);
    a.w = (1.0f - (float)mv.w) * (-10000.0f * L2E);
    reinterpret_cast<float4*>(Adm)[i] = a;
  }

  // Q fragments in registers for the whole kv loop
  const int qrow = q0 + w * 16 + lo;
  bf16x8 qf[2];
  qf[0] = *reinterpret_cast<const bf16x8*>(Qh + (size_t)qrow * HDc + hi * 8);
  qf[1] = *reinterpret_cast<const bf16x8*>(Qh + (size_t)qrow * HDc + 32 + hi * 8);

  bf16x8 onesf;
#pragma unroll
  for (int i = 0; i < 8; ++i) onesf[i] = (short)0x3F80;   // bf16 1.0

  f32x4 oacc[4] = {};
  f32x4 lacc = {};
  float mrow[4] = {-1e30f, -1e30f, -1e30f, -1e30f};

  const int ch1 = tid, row1 = ch1 >> 3, cg1 = (ch1 & 7) ^ (row1 & 7);
  const int ch2 = tid + 256, row2 = ch2 >> 3, cg2 = (ch2 & 7) ^ (row2 & 7);

  __syncthreads();                            // drains vmcnt(0): Q + adder loads

  // prologue: stage tile 0 into buffer 0
  gload_lds16(Kh + (size_t)row1 * HDc + cg1 * 8, &Ksm[0][0] + ch1 * 8);
  gload_lds16(Kh + (size_t)row2 * HDc + cg2 * 8, &Ksm[0][0] + ch2 * 8);
  gload_lds16(Vh + (size_t)row1 * Sc + cg1 * 8, &Vsm[0][0] + ch1 * 8);
  gload_lds16(Vh + (size_t)row2 * Sc + cg2 * 8, &Vsm[0][0] + ch2 * 8);

  int cur = 0;
  constexpr int NT = Sc / 64;
  for (int t = 0; t < NT; ++t) {
    if (t + 1 < NT) {
      const int kvn = (t + 1) * 64;
      u16* Kn = &Ksm[cur ^ 1][0];
      u16* Vn = &Vsm[cur ^ 1][0];
      gload_lds16(Kh + (size_t)(kvn + row1) * HDc + cg1 * 8, Kn + ch1 * 8);
      gload_lds16(Kh + (size_t)(kvn + row2) * HDc + cg2 * 8, Kn + ch2 * 8);
      gload_lds16(Vh + (size_t)row1 * Sc + kvn + cg1 * 8, Vn + ch1 * 8);
      gload_lds16(Vh + (size_t)row2 * Sc + kvn + cg2 * 8, Vn + ch2 * 8);
      asm volatile("s_waitcnt vmcnt(4)" ::: "memory");   // current tile resident
    } else {
      asm volatile("s_waitcnt vmcnt(0)" ::: "memory");
    }
    __builtin_amdgcn_sched_barrier(0);
    __builtin_amdgcn_s_barrier();
    __builtin_amdgcn_sched_barrier(0);

    const u16* Ks = &Ksm[cur][0];
    const u16* Vs = &Vsm[cur][0];

    // S = Q K^T (log2 units)
    f32x4 sacc[4] = {};
#pragma unroll
    for (int n = 0; n < 4; ++n) {
#pragma unroll
      for (int ks = 0; ks < 2; ++ks) {
        int row = n * 16 + lo;
        bf16x8 kf = *reinterpret_cast<const bf16x8*>(
            Ks + row * 64 + (((ks * 4 + hi) ^ (row & 7)) * 8));
        sacc[n] = __builtin_amdgcn_mfma_f32_16x16x32_bf16(qf[ks], kf, sacc[n], 0, 0, 0);
      }
      float add = Adm[t * 64 + n * 16 + lo];
#pragma unroll
      for (int r = 0; r < 4; ++r) sacc[n][r] += add;
    }

    // online softmax, log2 domain
    float tmax[4];
#pragma unroll
    for (int r = 0; r < 4; ++r)
      tmax[r] = fmaxf(fmaxf(sacc[0][r], sacc[1][r]), fmaxf(sacc[2][r], sacc[3][r]));
#pragma unroll
    for (int off = 1; off < 16; off <<= 1)
#pragma unroll
      for (int r = 0; r < 4; ++r) tmax[r] = fmaxf(tmax[r], __shfl_xor(tmax[r], off, 64));

    float scale[4];
#pragma unroll
    for (int r = 0; r < 4; ++r) {
      float mnew = fmaxf(mrow[r], tmax[r]);
      scale[r] = exp2f(mrow[r] - mnew);
      mrow[r] = mnew;
    }
#pragma unroll
    for (int n = 0; n < 4; ++n)
#pragma unroll
      for (int r = 0; r < 4; ++r) sacc[n][r] = exp2f(sacc[n][r] - mrow[r]);
#pragma unroll
    for (int n = 0; n < 4; ++n)
#pragma unroll
      for (int r = 0; r < 4; ++r) oacc[n][r] *= scale[r];
#pragma unroll
    for (int r = 0; r < 4; ++r) lacc[r] *= scale[r];

    // pack P (cvt_pk pairs) into per-wave swizzled LDS
    u16* Pw = &Psm[w][0];
#pragma unroll
    for (int n = 0; n < 4; ++n) {
      unsigned u01 = f2bf2(sacc[n][0], sacc[n][1]);
      unsigned u23 = f2bf2(sacc[n][2], sacc[n][3]);
      int pcol = n * 16 + lo;
      int r0 = hi * 4;
      Pw[(r0 + 0) * 64 + (pcol ^ (((r0 + 0) & 7) << 3))] = (u16)(u01 & 0xffff);
      Pw[(r0 + 1) * 64 + (pcol ^ (((r0 + 1) & 7) << 3))] = (u16)(u01 >> 16);
      Pw[(r0 + 2) * 64 + (pcol ^ (((r0 + 2) & 7) << 3))] = (u16)(u23 & 0xffff);
      Pw[(r0 + 3) * 64 + (pcol ^ (((r0 + 3) & 7) << 3))] = (u16)(u23 >> 16);
    }

    // PV + row-sum (ones-MFMA); pf hoisted (2 reads, not 8)
    bf16x8 pf0 = *reinterpret_cast<const bf16x8*>(
        Pw + lo * 64 + ((hi * 8) ^ ((lo & 7) << 3)));
    bf16x8 pf1 = *reinterpret_cast<const bf16x8*>(
        Pw + lo * 64 + ((32 + hi * 8) ^ ((lo & 7) << 3)));
    lacc = __builtin_amdgcn_mfma_f32_16x16x32_bf16(pf0, onesf, lacc, 0, 0, 0);
    lacc = __builtin_amdgcn_mfma_f32_16x16x32_bf16(pf1, onesf, lacc, 0, 0, 0);
#pragma unroll
    for (int n = 0; n < 4; ++n) {
      int vrow = n * 16 + lo;
      bf16x8 vf0 = *reinterpret_cast<const bf16x8*>(
          Vs + vrow * 64 + ((hi ^ (vrow & 7)) * 8));
      bf16x8 vf1 = *reinterpret_cast<const bf16x8*>(
          Vs + vrow * 64 + (((4 + hi) ^ (vrow & 7)) * 8));
      oacc[n] = __builtin_amdgcn_mfma_f32_16x16x32_bf16(pf0, vf0, oacc[n], 0, 0, 0);
      oacc[n] = __builtin_amdgcn_mfma_f32_16x16x32_bf16(pf1, vf1, oacc[n], 0, 0, 0);
    }

    __builtin_amdgcn_sched_barrier(0);
    __builtin_amdgcn_s_barrier();
    __builtin_amdgcn_sched_barrier(0);
    cur ^= 1;
  }

  // finalize: divide by l, write ctx[b,s, h*64+d] bf16
#pragma unroll
  for (int r = 0; r < 4; ++r) {
    float inv = 1.0f / lacc[r];
#pragma unroll
    for (int n = 0; n < 4; ++n) {
      int gq = q0 + w * 16 + hi * 4 + r;
      int gd = n * 16 + lo;
      ctxg[(size_t)(b * Sc + gq) * Hc + h * HDc + gd] = f2bf(oacc[n][r] * inv);
    }
  }
}

// ---------------- launch ----------------

extern "C" void kernel_launch(void* const* d_in, const int* in_sizes, int n_in,
                              void* d_out, int out_size, void* d_ws, size_t ws_size,
                              hipStream_t stream) {
  const float* hs  = (const float*)d_in[0];
  const int* mask  = (const int*)d_in[1];
  const float* Wq  = (const float*)d_in[2];
  const float* bq  = (const float*)d_in[3];
  const float* Wk  = (const float*)d_in[4];
  const float* bk  = (const float*)d_in[5];
  const float* Wv  = (const float*)d_in[6];
  const float* bv  = (const float*)d_in[7];
  const float* Wo  = (const float*)d_in[8];
  const float* bo  = (const float*)d_in[9];

  char* ws = (char*)d_ws;
  u16* Xb  = (u16*)(ws);                      // 4096x768 bf16
  u16* Wtq = (u16*)(ws + 6291456);            // 4x 768x768 bf16
  u16* Wtk = Wtq + 589824;
  u16* Wtv = Wtk + 589824;
  u16* Wto = Wtv + 589824;
  u16* Qb  = (u16*)(ws + 11010048);           // [24][2048][64]
  u16* Kb  = Qb + 3145728;                    // [24][2048][64]
  u16* Vtb = Kb + 3145728;                    // [24][64][2048]
  u16* Ctx = Vtb + 3145728;                   // 4096x768 bf16

  cvt_bf16<<<(Mc * Hc / 4 + 255) / 256, 256, 0, stream>>>(hs, Xb, Mc * Hc / 4);
  wtrans<<<dim3(24, 24, 4), dim3(32, 8), 0, stream>>>(Wq, Wk, Wv, Wo, Wtq, Wtk, Wtv, Wto);
  qkv_gemm<<<dim3(32, 6, 3), 256, 0, stream>>>(Xb, Wtq, Wtk, Wtv, bq, bk, bv, Qb, Kb, Vtb);
  attn<<<768, 256, 0, stream>>>(Qb, Kb, Vtb, mask, Ctx);
  out_gemm<<<dim3(32, 6), 256, 0, stream>>>(Ctx, Wto, bo, (float*)d_out);
}